// Round 1
// baseline (4052.987 us; speedup 1.0000x reference)
//
#include <hip/hip_runtime.h>

#define NN 50000
#define D 128
#define RR 4
#define NNZ 800000

// ---------------------------------------------------------------------------
// GEMV tile kernel: out_row[n][j] = sum_d x[n][d] * W[j][d]   (x @ W.T)
// MODE 0: write to z buffer slot 0 (stride 640) and zero slots 1..4
// MODE 1: write h[n*128+j] = result * odn[n]
// Block 256 threads, 16 nodes per block (2 groups of 128 threads x 8 nodes).
// ---------------------------------------------------------------------------
template <int MODE>
__global__ __launch_bounds__(256) void gemv_kernel(
    const float* __restrict__ x, const float* __restrict__ W,
    const float* __restrict__ odn, float* __restrict__ out)
{
    __shared__ float WT[D][D + 1];    // WT[d][j] = W[j][d], pad -> conflict-free
    __shared__ float xs[16][132];     // 132 pad: keeps float4 alignment (528B rows)

    const int t = threadIdx.x;
    // stage W transposed (coalesced global read; padded LDS write, conflict-free)
    for (int k = t; k < D * D; k += 256) {
        int j = k >> 7, d = k & 127;
        WT[d][j] = W[k];
    }
    const int n0 = blockIdx.x * 16;
    for (int k = t; k < 16 * D; k += 256) {
        int m = k >> 7, d = k & 127;
        xs[m][d] = x[(size_t)(n0 + m) * D + d];   // 50000 % 16 covered: 3125*16 exact
    }
    __syncthreads();

    const int j  = t & 127;
    const int mg = t >> 7;            // node sub-group (0/1)
    float acc[8];
#pragma unroll
    for (int m = 0; m < 8; ++m) acc[m] = 0.f;

    for (int d0 = 0; d0 < D; d0 += 4) {
        float4 xv[8];
#pragma unroll
        for (int m = 0; m < 8; ++m)
            xv[m] = *(const float4*)&xs[mg * 8 + m][d0];   // LDS broadcast, 16B
#pragma unroll
        for (int dd = 0; dd < 4; ++dd) {
            float w = WT[d0 + dd][j];                      // conflict-free (pad)
#pragma unroll
            for (int m = 0; m < 8; ++m) {
                float zv = (&xv[m].x)[dd];                 // static index (unrolled)
                acc[m] += zv * w;
            }
        }
    }

#pragma unroll
    for (int m = 0; m < 8; ++m) {
        int n = n0 + mg * 8 + m;
        if (MODE == 0) {
            out[(size_t)n * 640 + j] = acc[m];
#pragma unroll
            for (int r = 1; r <= 4; ++r) out[(size_t)n * 640 + r * 128 + j] = 0.f;
        } else {
            out[(size_t)n * D + j] = acc[m] * odn[n];
        }
    }
}

// ---------------------------------------------------------------------------
// COO scatter: z[row][slot*128 + d] += h[col][d]. One 64-lane wave per edge,
// 2 floats per lane. unsafeAtomicAdd -> global_atomic_add_f32 (no CAS loop).
// ---------------------------------------------------------------------------
__global__ __launch_bounds__(256) void scatter_kernel(
    const float* __restrict__ h, const int* __restrict__ rows,
    const int* __restrict__ cols, float* __restrict__ z, int slot)
{
    const int ln  = threadIdx.x & 63;
    const int wid = (blockIdx.x << 2) | (threadIdx.x >> 6);
    const int nwaves = gridDim.x << 2;
    for (int e = wid; e < NNZ; e += nwaves) {
        int row = rows[e], col = cols[e];
        float2 v = *(const float2*)&h[(size_t)col * D + ln * 2];
        float* dst = z + (size_t)row * 640 + slot * 128 + ln * 2;
        unsafeAtomicAdd(dst, v.x);
        unsafeAtomicAdd(dst + 1, v.y);
    }
}

// ---------------------------------------------------------------------------
// Per-node interaction. Block = 384 threads = 3 groups x 128 threads; each
// group owns one node per iteration. WC/WD staged in LDS (128 KB). Thread t
// owns output column d' = t&127 and keeps zc[r], zd[r] (r=0..4) in registers.
// ---------------------------------------------------------------------------
__global__ __launch_bounds__(384) void interact_kernel(
    float* __restrict__ z,           // d_out [N][640], in-place
    const float* __restrict__ WC, const float* __restrict__ WD,
    const float* __restrict__ att_w, const float* __restrict__ att_b,
    const float* __restrict__ idn, int iters)
{
    __shared__ float WCs[D * D];     // [d][d'] row-major, lanes -> consecutive d'
    __shared__ float WDs[D * D];
    __shared__ float z3s[3][5][132];
    __shared__ float zcs[3][5][132];
    __shared__ float zds[3][5][132];
    __shared__ float dots[3][2][25]; // [group][0=com/1=dis-dd][r*5+s]
    __shared__ float betas[3][2];

    const int t  = threadIdx.x;
    const int g  = t >> 7;           // group 0..2
    const int tl = t & 127;          // column d'
    const int wv = tl >> 6;          // wave within group
    const int ln = tl & 63;

    for (int k = t; k < D * D; k += 384) { WCs[k] = WC[k]; WDs[k] = WD[k]; }

    // hoist attention weights for this thread's columns
    float awc[5], awd[5];
#pragma unroll
    for (int r = 0; r < 5; ++r) {
        awc[r] = att_w[r * 128 + tl];
        awd[r] = att_w[640 + r * 128 + tl];
    }
    const float ab = att_b[0];

    for (int it = 0; it < iters; ++it) {
        const int n = ((size_t)it * gridDim.x + blockIdx.x) * 3 + g;
        const bool act = (n < NN);
        const float nf = act ? idn[n] : 0.f;
#pragma unroll
        for (int r = 0; r < 5; ++r)
            z3s[g][r][tl] = act ? z[(size_t)n * 640 + r * 128 + tl] * nf : 0.f;
        __syncthreads();

        // matvec: zc[r][tl] = sum_d z3[r][d]*WC[d][tl]; same for WD
        float ac[5] = {0, 0, 0, 0, 0}, ad[5] = {0, 0, 0, 0, 0};
        for (int d0 = 0; d0 < D; d0 += 4) {
            float4 zr[5];
#pragma unroll
            for (int r = 0; r < 5; ++r) zr[r] = *(const float4*)&z3s[g][r][d0];
#pragma unroll
            for (int dd = 0; dd < 4; ++dd) {
                float wc = WCs[(d0 + dd) * 128 + tl];
                float wd = WDs[(d0 + dd) * 128 + tl];
#pragma unroll
                for (int r = 0; r < 5; ++r) {
                    float zv = (&zr[r].x)[dd];
                    ac[r] += zv * wc;
                    ad[r] += zv * wd;
                }
            }
        }
#pragma unroll
        for (int r = 0; r < 5; ++r) { zcs[g][r][tl] = ac[r]; zds[g][r][tl] = ad[r]; }
        __syncthreads();

        // 15 unique symmetric dots per matrix; wave0 -> com, wave1 -> dis(dd)
        {
            const float* buf = (wv == 0) ? &zcs[g][0][0] : &zds[g][0][0];
            for (int r = 0; r < 5; ++r)
                for (int s = r; s < 5; ++s) {
                    float p = buf[r * 132 + ln] * buf[s * 132 + ln]
                            + buf[r * 132 + 64 + ln] * buf[s * 132 + 64 + ln];
#pragma unroll
                    for (int off = 32; off; off >>= 1) p += __shfl_xor(p, off);
                    if (ln == 0) {
                        dots[g][wv][r * 5 + s] = p;
                        dots[g][wv][s * 5 + r] = p;
                    }
                }
        }
        __syncthreads();

        // per-thread redundant softmax + combines (rows sequential: low regs)
        float zcom[5], zdis[5];
#pragma unroll
        for (int r = 0; r < 5; ++r) {
            // --- com row ---
            float sc[5], m = -1e30f;
#pragma unroll
            for (int s = 0; s < 5; ++s) { sc[s] = dots[g][0][r * 5 + s]; m = fmaxf(m, sc[s]); }
            float se = 0.f, e[5];
#pragma unroll
            for (int s = 0; s < 5; ++s) { e[s] = __expf(sc[s] - m); se += e[s]; }
            float inv = 1.f / se, accv = 0.f;
#pragma unroll
            for (int s = 0; s < 5; ++s) accv += e[s] * ac[s];
            zcom[r] = accv * inv;
            // --- dis row: score[r][s] = dd[r][r] - dd[r][s] ---
            float q = dots[g][1][r * 5 + r];
            float md = -1e30f, sd[5];
#pragma unroll
            for (int s = 0; s < 5; ++s) { sd[s] = q - dots[g][1][r * 5 + s]; md = fmaxf(md, sd[s]); }
            float sed = 0.f, ed[5];
#pragma unroll
            for (int s = 0; s < 5; ++s) { ed[s] = __expf(sd[s] - md); sed += ed[s]; }
            float invd = 1.f / sed, accd = 0.f;
#pragma unroll
            for (int s = 0; s < 5; ++s) accd += ed[s] * ad[s];
            zdis[r] = ad[r] - accd * invd;   // sum_s a*(zd[r]-zd[s]) = zd[r] - sum a*zd[s]
        }

        // beta = sigmoid(att_w . [z_com, z_dis] + att_b): block(group)-reduce
        float part = 0.f;
#pragma unroll
        for (int r = 0; r < 5; ++r) part += awc[r] * zcom[r] + awd[r] * zdis[r];
#pragma unroll
        for (int off = 32; off; off >>= 1) part += __shfl_xor(part, off);
        if (ln == 0) betas[g][wv] = part;
        __syncthreads();
        float barg = betas[g][0] + betas[g][1] + ab;
        float beta = 1.f / (1.f + __expf(-barg));

        if (act) {
#pragma unroll
            for (int r = 0; r < 5; ++r)
                z[(size_t)n * 640 + r * 128 + tl] = beta * zcom[r] + (1.f - beta) * zdis[r];
        }
        __syncthreads();   // protect LDS buffers before next iteration overwrites
    }
}

// ---------------------------------------------------------------------------
extern "C" void kernel_launch(void* const* d_in, const int* in_sizes, int n_in,
                              void* d_out, int out_size, void* d_ws, size_t ws_size,
                              hipStream_t stream)
{
    const float* x      = (const float*)d_in[0];
    const float* W_self = (const float*)d_in[1];
    const float* W_ring = (const float*)d_in[2];
    const float* WC     = (const float*)d_in[3];
    const float* WD     = (const float*)d_in[4];
    const float* att_w  = (const float*)d_in[5];
    const float* att_b  = (const float*)d_in[6];
    const float* odn    = (const float*)d_in[7];
    const float* idn    = (const float*)d_in[8];
    const int*   rows   = (const int*)d_in[9];
    const int*   cols   = (const int*)d_in[10];
    float* out = (float*)d_out;
    float* h   = (float*)d_ws;           // 50000*128*4 = 25.6 MB scratch

    // z_self into slot 0, zero ring slots (d_out is poisoned 0xAA)
    gemv_kernel<0><<<NN / 16, 256, 0, stream>>>(x, W_self, nullptr, out);

    for (int r = 0; r < RR; ++r) {
        gemv_kernel<1><<<NN / 16, 256, 0, stream>>>(x, W_ring + (size_t)r * D * D, odn, h);
        scatter_kernel<<<4096, 256, 0, stream>>>(h, rows + (size_t)r * NNZ,
                                                 cols + (size_t)r * NNZ, out, r + 1);
    }

    const int gridC = 1024;
    const int iters = (NN + gridC * 3 - 1) / (gridC * 3);
    interact_kernel<<<gridC, 384, 0, stream>>>(out, WC, WD, att_w, att_b, idn, iters);
}

// Round 2
// 1446.207 us; speedup vs baseline: 2.8025x; 2.8025x over previous
//
#include <hip/hip_runtime.h>

#define NN 50000
#define D 128
#define RR 4
#define NNZ 800000
#define NCHUNK 196            // ceil(NN/256)

// ============================ CSR build =====================================
__global__ __launch_bounds__(256) void zero_kernel(int* __restrict__ p, int n)
{
    int i = blockIdx.x * 256 + threadIdx.x;
    if (i < n) p[i] = 0;
}

__global__ __launch_bounds__(256) void hist_kernel(
    const int* __restrict__ rows, int* __restrict__ cnt)
{
    const int r = blockIdx.y;
    const int e = blockIdx.x * 256 + threadIdx.x;      // NNZ = 3125*256 exact
    atomicAdd(&cnt[r * NN + rows[(size_t)r * NNZ + e]], 1);
}

__global__ __launch_bounds__(256) void scanA_kernel(
    const int* __restrict__ cnt, int* __restrict__ bsum)
{
    const int r = blockIdx.y, bx = blockIdx.x, t = threadIdx.x;
    const int idx = bx * 256 + t;
    int v = (idx < NN) ? cnt[r * NN + idx] : 0;
#pragma unroll
    for (int off = 32; off; off >>= 1) v += __shfl_xor(v, off);
    __shared__ int ws4[4];
    if ((t & 63) == 0) ws4[t >> 6] = v;
    __syncthreads();
    if (t == 0) bsum[r * NCHUNK + bx] = ws4[0] + ws4[1] + ws4[2] + ws4[3];
}

__global__ __launch_bounds__(256) void scanB_kernel(int* __restrict__ bsum)
{
    __shared__ int s[256];
    const int t = threadIdx.x;
    for (int r = 0; r < RR; ++r) {
        int v = (t < NCHUNK) ? bsum[r * NCHUNK + t] : 0;
        s[t] = v;
        __syncthreads();
        for (int off = 1; off < 256; off <<= 1) {
            int u = (t >= off) ? s[t - off] : 0;
            __syncthreads();
            s[t] += u;
            __syncthreads();
        }
        if (t < NCHUNK) bsum[r * NCHUNK + t] = s[t] - v;   // exclusive
        __syncthreads();
    }
}

__global__ __launch_bounds__(256) void scanC_kernel(
    const int* __restrict__ cnt, const int* __restrict__ bsum,
    int* __restrict__ rowptr, int* __restrict__ cursor)
{
    const int r = blockIdx.y, bx = blockIdx.x, t = threadIdx.x;
    const int idx = bx * 256 + t;
    int v = (idx < NN) ? cnt[r * NN + idx] : 0;
    __shared__ int s[256];
    s[t] = v;
    __syncthreads();
    for (int off = 1; off < 256; off <<= 1) {
        int u = (t >= off) ? s[t - off] : 0;
        __syncthreads();
        s[t] += u;
        __syncthreads();
    }
    const int excl = bsum[r * NCHUNK + bx] + s[t] - v;
    if (idx <= NN) rowptr[r * (NN + 1) + idx] = excl;
    if (idx < NN)  cursor[r * NN + idx] = excl;
}

__global__ __launch_bounds__(256) void fill_kernel(
    const int* __restrict__ rows, const int* __restrict__ cols,
    int* __restrict__ cursor, int* __restrict__ perm)
{
    const int r = blockIdx.y;
    const int e = blockIdx.x * 256 + threadIdx.x;
    const int row = rows[(size_t)r * NNZ + e];
    const int pos = atomicAdd(&cursor[r * NN + row], 1);
    perm[(size_t)r * NNZ + pos] = cols[(size_t)r * NNZ + e];
}

// ============================ GEMV ==========================================
// out_row[n][j] = sum_d x[n][d] * W[j][d]   (x @ W.T)
// MODE 0: write z-slot 0 (stride 640).  MODE 1: h[n*128+j] = result * odn[n].
template <int MODE>
__global__ __launch_bounds__(256) void gemv_kernel(
    const float* __restrict__ x, const float* __restrict__ W,
    const float* __restrict__ odn, float* __restrict__ out)
{
    __shared__ float WT[D][D + 1];
    __shared__ float xs[16][132];

    const int t = threadIdx.x;
    for (int k = t; k < D * D; k += 256) {
        int j = k >> 7, d = k & 127;
        WT[d][j] = W[k];
    }
    const int n0 = blockIdx.x * 16;
    for (int k = t; k < 16 * D; k += 256) {
        int m = k >> 7, d = k & 127;
        xs[m][d] = x[(size_t)(n0 + m) * D + d];
    }
    __syncthreads();

    const int j  = t & 127;
    const int mg = t >> 7;
    float acc[8];
#pragma unroll
    for (int m = 0; m < 8; ++m) acc[m] = 0.f;

    for (int d0 = 0; d0 < D; d0 += 4) {
        float4 xv[8];
#pragma unroll
        for (int m = 0; m < 8; ++m)
            xv[m] = *(const float4*)&xs[mg * 8 + m][d0];
#pragma unroll
        for (int dd = 0; dd < 4; ++dd) {
            float w = WT[d0 + dd][j];
#pragma unroll
            for (int m = 0; m < 8; ++m) {
                float zv = (&xv[m].x)[dd];
                acc[m] += zv * w;
            }
        }
    }

#pragma unroll
    for (int m = 0; m < 8; ++m) {
        int n = n0 + mg * 8 + m;
        if (MODE == 0) out[(size_t)n * 640 + j] = acc[m];
        else           out[(size_t)n * D + j] = acc[m] * odn[n];
    }
}

// ============================ CSR gather ====================================
// z[row][slot*128+d] = sum over CSR edges of h[col][d]. One wave per row.
__global__ __launch_bounds__(256) void gather_kernel(
    const float* __restrict__ h, const int* __restrict__ rp,
    const int* __restrict__ pm, float* __restrict__ z, int slot)
{
    const int ln  = threadIdx.x & 63;
    const int row = blockIdx.x * 4 + (threadIdx.x >> 6);   // 12500*4 = 50000 exact
    const int s = rp[row], e = rp[row + 1];
    float2 acc = make_float2(0.f, 0.f);
    int i = s;
    for (; i + 4 <= e; i += 4) {                           // 4 loads in flight
        int c0 = pm[i], c1 = pm[i + 1], c2 = pm[i + 2], c3 = pm[i + 3];
        float2 v0 = *(const float2*)&h[(size_t)c0 * D + ln * 2];
        float2 v1 = *(const float2*)&h[(size_t)c1 * D + ln * 2];
        float2 v2 = *(const float2*)&h[(size_t)c2 * D + ln * 2];
        float2 v3 = *(const float2*)&h[(size_t)c3 * D + ln * 2];
        acc.x += v0.x + v1.x + v2.x + v3.x;
        acc.y += v0.y + v1.y + v2.y + v3.y;
    }
    for (; i < e; ++i) {
        int c = pm[i];
        float2 v = *(const float2*)&h[(size_t)c * D + ln * 2];
        acc.x += v.x; acc.y += v.y;
    }
    *(float2*)&z[(size_t)row * 640 + slot * 128 + ln * 2] = acc;
}

// ============================ interaction ===================================
// Wave-per-node: 1024 threads = 16 independent waves, no barriers in the loop.
// Lane ln owns output columns ln and ln+64. WC/WD staged as packed float2.
__device__ __forceinline__ int sidx(int r, int s)
{
    if (r > s) { int t = r; r = s; s = t; }
    return r * 5 + s - (r * (r + 1)) / 2;      // symmetric 15-element index
}

__global__ __launch_bounds__(1024, 4) void interact_kernel(
    float* __restrict__ z,
    const float* __restrict__ WC, const float* __restrict__ WD,
    const float* __restrict__ att_w, const float* __restrict__ att_b,
    const float* __restrict__ idn, int iters)
{
    __shared__ float2 WCp[D * 64];     // [d][ln] = {W[d][ln], W[d][ln+64]}
    __shared__ float2 WDp[D * 64];
    const int t = threadIdx.x;
    for (int k = t; k < D * 64; k += 1024) {
        int d = k >> 6, l = k & 63;
        WCp[k] = make_float2(WC[d * 128 + l], WC[d * 128 + 64 + l]);
        WDp[k] = make_float2(WD[d * 128 + l], WD[d * 128 + 64 + l]);
    }
    __syncthreads();

    const int w  = t >> 6;
    const int ln = t & 63;
    const float ab = att_b[0];

    for (int it = 0; it < iters; ++it) {
        const int n = (it * gridDim.x + blockIdx.x) * 16 + w;
        if (n >= NN) break;                    // monotone in it; no barriers below
        const float nf = idn[n];
        const float* zn = z + (size_t)n * 640;

        // ---- matvec: ac = z_row @ WC, ad = z_row @ WD (nf applied after) ----
        float2 ac[5], ad[5];
#pragma unroll
        for (int r = 0; r < 5; ++r) { ac[r] = make_float2(0.f, 0.f); ad[r] = make_float2(0.f, 0.f); }
        for (int d0 = 0; d0 < D; d0 += 4) {
            float4 zr[5];
#pragma unroll
            for (int r = 0; r < 5; ++r) zr[r] = *(const float4*)(zn + r * 128 + d0);
#pragma unroll
            for (int dd = 0; dd < 4; ++dd) {
                float2 wc = WCp[(d0 + dd) * 64 + ln];
                float2 wd = WDp[(d0 + dd) * 64 + ln];
#pragma unroll
                for (int r = 0; r < 5; ++r) {
                    float zv = (&zr[r].x)[dd];
                    ac[r].x += zv * wc.x; ac[r].y += zv * wc.y;
                    ad[r].x += zv * wd.x; ad[r].y += zv * wd.y;
                }
            }
        }
#pragma unroll
        for (int r = 0; r < 5; ++r) {
            ac[r].x *= nf; ac[r].y *= nf;
            ad[r].x *= nf; ad[r].y *= nf;
        }

        // ---- 15 symmetric dots per matrix, reduced across the wave ----
        float pc[15], pd[15];
        {
            int k = 0;
#pragma unroll
            for (int r = 0; r < 5; ++r)
#pragma unroll
                for (int s = r; s < 5; ++s, ++k) {
                    float vc = ac[r].x * ac[s].x + ac[r].y * ac[s].y;
                    float vd = ad[r].x * ad[s].x + ad[r].y * ad[s].y;
#pragma unroll
                    for (int off = 32; off; off >>= 1) {
                        vc += __shfl_xor(vc, off);
                        vd += __shfl_xor(vd, off);
                    }
                    pc[k] = vc; pd[k] = vd;
                }
        }

        // ---- per-lane softmaxes + combines ----
        float2 zcom[5], zdis[5];
#pragma unroll
        for (int r = 0; r < 5; ++r) {
            float sc[5], m = -1e30f;
#pragma unroll
            for (int s = 0; s < 5; ++s) { sc[s] = pc[sidx(r, s)]; m = fmaxf(m, sc[s]); }
            float e[5], se = 0.f;
#pragma unroll
            for (int s = 0; s < 5; ++s) { e[s] = __expf(sc[s] - m); se += e[s]; }
            float inv = 1.f / se, axx = 0.f, ayy = 0.f;
#pragma unroll
            for (int s = 0; s < 5; ++s) { axx += e[s] * ac[s].x; ayy += e[s] * ac[s].y; }
            zcom[r].x = axx * inv; zcom[r].y = ayy * inv;

            float q = pd[sidx(r, r)];
            float sd[5], md = -1e30f;
#pragma unroll
            for (int s = 0; s < 5; ++s) { sd[s] = q - pd[sidx(r, s)]; md = fmaxf(md, sd[s]); }
            float ed[5], sed = 0.f;
#pragma unroll
            for (int s = 0; s < 5; ++s) { ed[s] = __expf(sd[s] - md); sed += ed[s]; }
            float invd = 1.f / sed, dxx = 0.f, dyy = 0.f;
#pragma unroll
            for (int s = 0; s < 5; ++s) { dxx += ed[s] * ad[s].x; dyy += ed[s] * ad[s].y; }
            zdis[r].x = ad[r].x - dxx * invd;      // sum_s a*(zd_r - zd_s)
            zdis[r].y = ad[r].y - dyy * invd;
        }

        // ---- beta = sigmoid(att_w . [z_com, z_dis] + b) ----
        float part = 0.f;
#pragma unroll
        for (int r = 0; r < 5; ++r) {
            part += att_w[r * 128 + ln]            * zcom[r].x
                  + att_w[r * 128 + 64 + ln]       * zcom[r].y;
            part += att_w[640 + r * 128 + ln]      * zdis[r].x
                  + att_w[640 + r * 128 + 64 + ln] * zdis[r].y;
        }
#pragma unroll
        for (int off = 32; off; off >>= 1) part += __shfl_xor(part, off);
        const float beta = 1.f / (1.f + __expf(-(part + ab)));
        const float omb  = 1.f - beta;

        float* zo = z + (size_t)n * 640;
#pragma unroll
        for (int r = 0; r < 5; ++r) {
            zo[r * 128 + ln]      = beta * zcom[r].x + omb * zdis[r].x;
            zo[r * 128 + 64 + ln] = beta * zcom[r].y + omb * zdis[r].y;
        }
    }
}

// ============================ launch ========================================
extern "C" void kernel_launch(void* const* d_in, const int* in_sizes, int n_in,
                              void* d_out, int out_size, void* d_ws, size_t ws_size,
                              hipStream_t stream)
{
    const float* x      = (const float*)d_in[0];
    const float* W_self = (const float*)d_in[1];
    const float* W_ring = (const float*)d_in[2];
    const float* WC     = (const float*)d_in[3];
    const float* WD     = (const float*)d_in[4];
    const float* att_w  = (const float*)d_in[5];
    const float* att_b  = (const float*)d_in[6];
    const float* odn    = (const float*)d_in[7];
    const float* idn    = (const float*)d_in[8];
    const int*   rows   = (const int*)d_in[9];
    const int*   cols   = (const int*)d_in[10];
    float* out = (float*)d_out;

    // ---- workspace layout (≈41 MB) ----
    float* h      = (float*)d_ws;                       // 6,400,000 f32
    int*   cnt    = (int*)(h + (size_t)NN * D);         // 200,000
    int*   rowptr = cnt + RR * NN;                      // 200,004
    int*   cursor = rowptr + RR * (NN + 1);             // 200,000
    int*   bsum   = cursor + RR * NN;                   // 784 (+pad)
    int*   perm   = bsum + 1024;                        // 3,200,000

    // ---- CSR build (once per call; no deps on h) ----
    zero_kernel<<<(RR * NN + 255) / 256, 256, 0, stream>>>(cnt, RR * NN);
    hist_kernel<<<dim3(NNZ / 256, RR), 256, 0, stream>>>(rows, cnt);
    scanA_kernel<<<dim3(NCHUNK, RR), 256, 0, stream>>>(cnt, bsum);
    scanB_kernel<<<1, 256, 0, stream>>>(bsum);
    scanC_kernel<<<dim3(NCHUNK, RR), 256, 0, stream>>>(cnt, bsum, rowptr, cursor);
    fill_kernel<<<dim3(NNZ / 256, RR), 256, 0, stream>>>(rows, cols, cursor, perm);

    // ---- z_self into slot 0 ----
    gemv_kernel<0><<<NN / 16, 256, 0, stream>>>(x, W_self, nullptr, out);

    // ---- per ring: h = (x @ Wr.T)*odn, then CSR gather into slot r+1 ----
    for (int r = 0; r < RR; ++r) {
        gemv_kernel<1><<<NN / 16, 256, 0, stream>>>(x, W_ring + (size_t)r * D * D, odn, h);
        gather_kernel<<<NN / 4, 256, 0, stream>>>(h, rowptr + r * (NN + 1),
                                                  perm + (size_t)r * NNZ, out, r + 1);
    }

    // ---- fused per-node interaction (in-place on d_out) ----
    const int gridI = 256;
    const int iters = (NN + gridI * 16 - 1) / (gridI * 16);
    interact_kernel<<<gridI, 1024, 0, stream>>>(out, WC, WD, att_w, att_b, idn, iters);
}

// Round 4
// 1220.992 us; speedup vs baseline: 3.3194x; 1.1845x over previous
//
#include <hip/hip_runtime.h>
#include <hip/hip_bf16.h>

#define NN 50000
#define D 128
#define RR 4
#define NNZ 800000
#define NCHUNK 196            // ceil(NN/256)

typedef float v2f    __attribute__((ext_vector_type(2)));
typedef float f32x4  __attribute__((ext_vector_type(4)));
typedef short bf16x8 __attribute__((ext_vector_type(8)));

static __device__ __forceinline__ unsigned short f2b(float f)
{
    __hip_bfloat16 h = __float2bfloat16(f);      // RNE
    return *reinterpret_cast<unsigned short*>(&h);
}
static __device__ __forceinline__ float b2f(unsigned short u)
{
    union { unsigned u32; float f; } v; v.u32 = ((unsigned)u) << 16; return v.f;
}

// ============================ CSR build =====================================
__global__ __launch_bounds__(256) void hist_kernel(
    const int* __restrict__ rows, int* __restrict__ cnt)
{
    const int r = blockIdx.y;
    const int e = blockIdx.x * 256 + threadIdx.x;      // NNZ = 3125*256 exact
    atomicAdd(&cnt[r * NN + rows[(size_t)r * NNZ + e]], 1);
}

__global__ __launch_bounds__(256) void scanA_kernel(
    const int* __restrict__ cnt, int* __restrict__ bsum)
{
    const int r = blockIdx.y, bx = blockIdx.x, t = threadIdx.x;
    const int idx = bx * 256 + t;
    int v = (idx < NN) ? cnt[r * NN + idx] : 0;
#pragma unroll
    for (int off = 32; off; off >>= 1) v += __shfl_xor(v, off);
    __shared__ int ws4[4];
    if ((t & 63) == 0) ws4[t >> 6] = v;
    __syncthreads();
    if (t == 0) bsum[r * NCHUNK + bx] = ws4[0] + ws4[1] + ws4[2] + ws4[3];
}

__global__ __launch_bounds__(256) void scanB_kernel(int* __restrict__ bsum)
{
    __shared__ int s[256];
    const int t = threadIdx.x;
    for (int r = 0; r < RR; ++r) {
        int v = (t < NCHUNK) ? bsum[r * NCHUNK + t] : 0;
        s[t] = v;
        __syncthreads();
        for (int off = 1; off < 256; off <<= 1) {
            int u = (t >= off) ? s[t - off] : 0;
            __syncthreads();
            s[t] += u;
            __syncthreads();
        }
        if (t < NCHUNK) bsum[r * NCHUNK + t] = s[t] - v;   // exclusive
        __syncthreads();
    }
}

__global__ __launch_bounds__(256) void scanC_kernel(
    const int* __restrict__ cnt, const int* __restrict__ bsum,
    int* __restrict__ rowptr, int* __restrict__ cursor)
{
    const int r = blockIdx.y, bx = blockIdx.x, t = threadIdx.x;
    const int idx = bx * 256 + t;
    int v = (idx < NN) ? cnt[r * NN + idx] : 0;
    __shared__ int s[256];
    s[t] = v;
    __syncthreads();
    for (int off = 1; off < 256; off <<= 1) {
        int u = (t >= off) ? s[t - off] : 0;
        __syncthreads();
        s[t] += u;
        __syncthreads();
    }
    const int excl = bsum[r * NCHUNK + bx] + s[t] - v;
    if (idx <= NN) rowptr[r * (NN + 1) + idx] = excl;
    if (idx < NN)  cursor[r * NN + idx] = excl;
}

__global__ __launch_bounds__(256) void fill_kernel(
    const int* __restrict__ rows, const int* __restrict__ cols,
    int* __restrict__ cursor, int* __restrict__ perm)
{
    const int r = blockIdx.y;
    const int e = blockIdx.x * 256 + threadIdx.x;
    const int row = rows[(size_t)r * NNZ + e];
    const int pos = atomicAdd(&cursor[r * NN + row], 1);
    perm[(size_t)r * NNZ + pos] = cols[(size_t)r * NNZ + e];
}

// ============================ W split to bf16 hi/lo =========================
// wh/wl[jg*128+k]: jg<128 -> W_self[jg][k], else W_rings flat row jg-128
__global__ __launch_bounds__(256) void convw_kernel(
    const float* __restrict__ Wself, const float* __restrict__ Wrings,
    unsigned short* __restrict__ wh, unsigned short* __restrict__ wl)
{
    int idx = blockIdx.x * 256 + threadIdx.x;    // 81920 elements
    int jg = idx >> 7, k = idx & 127;
    float f = (jg < 128) ? Wself[(size_t)jg * 128 + k]
                         : Wrings[(size_t)(jg - 128) * 128 + k];
    unsigned short hi = f2b(f);
    wh[idx] = hi;
    wl[idx] = f2b(f - b2f(hi));
}

// ============================ split-bf16 MFMA GEMM ==========================
// out_full[n][jg] = sum_k x[n][k] * W_all[jg][k],  jg in [0,640).
// x loaded fp32, split hi/lo in-register; product = xh*Wh + xl*Wh + xh*Wl
// (error ~2^-16 relative -> fp32-quality z; softmax-score-safe).
// Block = 256 thr = 4 waves, M-tile 16 (grid 3125 exact), K=128 in 4 steps.
// Wave w handles col-tiles ct = ct0 + w + 4*j, j < nj.
// ct<8 -> out slot0 f32; ct>=8 -> ring r=(ct>>3)-1-ring0, h fp32 * odn.
// Frag layout (16x16x32): A: row=l&15, k=(l>>4)*8+j ; B: col=l&15, same k.
// C: col=l&15, row=(l>>4)*4+q  [m89-verified]
__global__ __launch_bounds__(256) void gemm_kernel(
    const float* __restrict__ x,
    const unsigned short* __restrict__ wh, const unsigned short* __restrict__ wl,
    const float* __restrict__ odn, float* __restrict__ out,
    float* __restrict__ h, int ct0, int nj, int ring0)
{
    const int t = threadIdx.x;
    const int w = t >> 6, l = t & 63;
    const int lr = l & 15, lk = l >> 4;
    const int n0 = blockIdx.x * 16;

    // ---- A fragments: load fp32 row chunk, split to bf16 hi/lo ----
    bf16x8 ah[4], al[4];
    const float* xr = x + (size_t)(n0 + lr) * D + lk * 8;
#pragma unroll
    for (int ks = 0; ks < 4; ++ks) {
        float4 v0 = *(const float4*)(xr + ks * 32);
        float4 v1 = *(const float4*)(xr + ks * 32 + 4);
        float f[8] = {v0.x, v0.y, v0.z, v0.w, v1.x, v1.y, v1.z, v1.w};
#pragma unroll
        for (int j = 0; j < 8; ++j) {
            unsigned short hi = f2b(f[j]);
            ah[ks][j] = (short)hi;
            al[ks][j] = (short)f2b(f[j] - b2f(hi));
        }
    }

    float od[4];
#pragma unroll
    for (int q = 0; q < 4; ++q) od[q] = odn[n0 + lk * 4 + q];

    for (int j = 0; j < nj; ++j) {
        const int ct = ct0 + w + 4 * j;
        const int colg = ct * 16 + lr;
        f32x4 acc = {0.f, 0.f, 0.f, 0.f};
#pragma unroll
        for (int ks = 0; ks < 4; ++ks) {
            bf16x8 bh = *(const bf16x8*)&wh[(size_t)colg * D + ks * 32 + lk * 8];
            bf16x8 bl = *(const bf16x8*)&wl[(size_t)colg * D + ks * 32 + lk * 8];
            acc = __builtin_amdgcn_mfma_f32_16x16x32_bf16(ah[ks], bh, acc, 0, 0, 0);
            acc = __builtin_amdgcn_mfma_f32_16x16x32_bf16(al[ks], bh, acc, 0, 0, 0);
            acc = __builtin_amdgcn_mfma_f32_16x16x32_bf16(ah[ks], bl, acc, 0, 0, 0);
        }
        if (ct < 8) {
#pragma unroll
            for (int q = 0; q < 4; ++q) {
                int n = n0 + lk * 4 + q;
                out[(size_t)n * 640 + colg] = acc[q];
            }
        } else {
            const int r = (ct >> 3) - 1 - ring0;
            const int d = (ct & 7) * 16 + lr;
#pragma unroll
            for (int q = 0; q < 4; ++q) {
                int n = n0 + lk * 4 + q;
                h[((size_t)r * NN + n) * D + d] = acc[q] * od[q];
            }
        }
    }
}

// ============================ CSR gather (fp32 h) ===========================
// h ring = blockIdx.y ; CSR ring = blockIdx.y + csr_base ; z slot = csr+1
__global__ __launch_bounds__(256) void gather_kernel(
    const float* __restrict__ h, const int* __restrict__ rp,
    const int* __restrict__ pm, float* __restrict__ z, int csr_base)
{
    const int hr = blockIdx.y;
    const int cr = hr + csr_base;
    const int ln = threadIdx.x & 63;
    const int row = blockIdx.x * 4 + (threadIdx.x >> 6);   // 12500*4 = 50000
    const int* rpr = rp + (size_t)cr * (NN + 1);
    const int s = rpr[row], e = rpr[row + 1];
    const float* hb = h + (size_t)hr * NN * D;
    const int* pmr = pm + (size_t)cr * NNZ;

    float2 acc = make_float2(0.f, 0.f);
    int i = s;
    for (; i + 4 <= e; i += 4) {                           // 4 loads in flight
        int c0 = pmr[i], c1 = pmr[i + 1], c2 = pmr[i + 2], c3 = pmr[i + 3];
        float2 v0 = *(const float2*)&hb[(size_t)c0 * D + ln * 2];
        float2 v1 = *(const float2*)&hb[(size_t)c1 * D + ln * 2];
        float2 v2 = *(const float2*)&hb[(size_t)c2 * D + ln * 2];
        float2 v3 = *(const float2*)&hb[(size_t)c3 * D + ln * 2];
        acc.x += v0.x + v1.x + v2.x + v3.x;
        acc.y += v0.y + v1.y + v2.y + v3.y;
    }
    for (; i < e; ++i) {
        float2 v = *(const float2*)&hb[(size_t)pmr[i] * D + ln * 2];
        acc.x += v.x; acc.y += v.y;
    }
    *(float2*)&z[(size_t)row * 640 + (cr + 1) * 128 + ln * 2] = acc;
}

// ============================ interaction ===================================
__device__ __forceinline__ int sidx(int r, int s)
{
    if (r > s) { int t = r; r = s; s = t; }
    return r * 5 + s - (r * (r + 1)) / 2;
}

__global__ __launch_bounds__(1024, 4) void interact_kernel(
    float* __restrict__ z,
    const float* __restrict__ WC, const float* __restrict__ WD,
    const float* __restrict__ att_w, const float* __restrict__ att_b,
    const float* __restrict__ idn, int iters)
{
    // WP[d*64+ln] = {WC[d][ln], WC[d][ln+64], WD[d][ln], WD[d][ln+64]}
    __shared__ f32x4 WP[D * 64];     // 128 KB, one ds_read_b128 per (d,ln)
    const int t = threadIdx.x;
    for (int k = t; k < D * 64; k += 1024) {
        int d = k >> 6, l = k & 63;
        WP[k] = (f32x4){WC[d * 128 + l], WC[d * 128 + 64 + l],
                        WD[d * 128 + l], WD[d * 128 + 64 + l]};
    }
    __syncthreads();

    const int w  = t >> 6;
    const int ln = t & 63;
    const float ab = att_b[0];

    v2f awc[5], awd[5];
#pragma unroll
    for (int r = 0; r < 5; ++r) {
        awc[r] = (v2f){att_w[r * 128 + ln], att_w[r * 128 + 64 + ln]};
        awd[r] = (v2f){att_w[640 + r * 128 + ln], att_w[640 + r * 128 + 64 + ln]};
    }

    for (int it = 0; it < iters; ++it) {
        const int n = (it * gridDim.x + blockIdx.x) * 16 + w;
        if (n >= NN) break;                    // no barriers below: waves free-run
        const float nf = idn[n];
        const float* zn = z + (size_t)n * 640;

        v2f ac[5], ad[5];
#pragma unroll
        for (int r = 0; r < 5; ++r) { ac[r] = (v2f)0.f; ad[r] = (v2f)0.f; }
        for (int d0 = 0; d0 < D; d0 += 4) {
            float4 zr[5];
#pragma unroll
            for (int r = 0; r < 5; ++r) zr[r] = *(const float4*)(zn + r * 128 + d0);
#pragma unroll
            for (int dd = 0; dd < 4; ++dd) {
                f32x4 wp = WP[(d0 + dd) * 64 + ln];
                v2f wc = (v2f){wp.x, wp.y};
                v2f wd = (v2f){wp.z, wp.w};
#pragma unroll
                for (int r = 0; r < 5; ++r) {
                    float zv = (&zr[r].x)[dd];
                    ac[r] += wc * zv;          // v_pk_fma_f32
                    ad[r] += wd * zv;
                }
            }
        }
#pragma unroll
        for (int r = 0; r < 5; ++r) { ac[r] *= nf; ad[r] *= nf; }

        float pc[15], pd[15];
        {
            int k = 0;
#pragma unroll
            for (int r = 0; r < 5; ++r)
#pragma unroll
                for (int s = r; s < 5; ++s, ++k) {
                    v2f qc = ac[r] * ac[s];
                    v2f qd = ad[r] * ad[s];
                    float vc = qc.x + qc.y;
                    float vd = qd.x + qd.y;
#pragma unroll
                    for (int off = 32; off; off >>= 1) {
                        vc += __shfl_xor(vc, off);
                        vd += __shfl_xor(vd, off);
                    }
                    pc[k] = vc; pd[k] = vd;
                }
        }

        v2f zcom[5], zdis[5];
#pragma unroll
        for (int r = 0; r < 5; ++r) {
            float sc[5], m = -1e30f;
#pragma unroll
            for (int s = 0; s < 5; ++s) { sc[s] = pc[sidx(r, s)]; m = fmaxf(m, sc[s]); }
            float e[5], se = 0.f;
#pragma unroll
            for (int s = 0; s < 5; ++s) { e[s] = __expf(sc[s] - m); se += e[s]; }
            float inv = 1.f / se;
            v2f a2 = (v2f)0.f;
#pragma unroll
            for (int s = 0; s < 5; ++s) a2 += ac[s] * e[s];
            zcom[r] = a2 * inv;

            float q = pd[sidx(r, r)];
            float sd[5], md = -1e30f;
#pragma unroll
            for (int s = 0; s < 5; ++s) { sd[s] = q - pd[sidx(r, s)]; md = fmaxf(md, sd[s]); }
            float ed[5], sed = 0.f;
#pragma unroll
            for (int s = 0; s < 5; ++s) { ed[s] = __expf(sd[s] - md); sed += ed[s]; }
            float invd = 1.f / sed;
            v2f d2 = (v2f)0.f;
#pragma unroll
            for (int s = 0; s < 5; ++s) d2 += ad[s] * ed[s];
            zdis[r] = ad[r] - d2 * invd;       // sum_s a*(zd_r - zd_s)
        }

        v2f p2 = (v2f)0.f;
#pragma unroll
        for (int r = 0; r < 5; ++r) p2 += awc[r] * zcom[r] + awd[r] * zdis[r];
        float part = p2.x + p2.y;
#pragma unroll
        for (int off = 32; off; off >>= 1) part += __shfl_xor(part, off);
        const float beta = 1.f / (1.f + __expf(-(part + ab)));
        const float omb  = 1.f - beta;

        float* zo = z + (size_t)n * 640;
#pragma unroll
        for (int r = 0; r < 5; ++r) {
            v2f o = zcom[r] * beta + zdis[r] * omb;
            zo[r * 128 + ln]      = o.x;
            zo[r * 128 + 64 + ln] = o.y;
        }
    }
}

// ============================ launch ========================================
extern "C" void kernel_launch(void* const* d_in, const int* in_sizes, int n_in,
                              void* d_out, int out_size, void* d_ws, size_t ws_size,
                              hipStream_t stream)
{
    const float* x      = (const float*)d_in[0];
    const float* W_self = (const float*)d_in[1];
    const float* W_ring = (const float*)d_in[2];
    const float* WC     = (const float*)d_in[3];
    const float* WD     = (const float*)d_in[4];
    const float* att_w  = (const float*)d_in[5];
    const float* att_b  = (const float*)d_in[6];
    const float* odn    = (const float*)d_in[7];
    const float* idn    = (const float*)d_in[8];
    const int*   rows   = (const int*)d_in[9];
    const int*   cols   = (const int*)d_in[10];
    float* out = (float*)d_out;

    // ---- workspace layout ----
    const size_t wb_sz  = (size_t)640 * 128 * 2;        // 160 KB each (wh, wl)
    const size_t h1_sz  = (size_t)NN * D * 4;           // 25.6 MB per ring (fp32)
    const size_t cnt_sz = (size_t)RR * NN * 4;
    const size_t rp_sz  = (size_t)RR * (NN + 1) * 4;
    const size_t cur_sz = (size_t)RR * NN * 4;
    const size_t bs_sz  = 4096;
    const size_t pm_sz  = (size_t)RR * NNZ * 4;
    const size_t fixed  = 2 * wb_sz + cnt_sz + rp_sz + cur_sz + bs_sz + pm_sz;
    const bool big = ws_size >= fixed + RR * h1_sz + 4096;   // ~118 MB
    // fallback path footprint ~41.3 MB == round-1/2 proven usage

    char* p = (char*)d_ws;
    unsigned short* wh = (unsigned short*)p; p += wb_sz;
    unsigned short* wl = (unsigned short*)p; p += wb_sz;
    float* h    = (float*)p; p += (big ? RR : 1) * h1_sz;
    int* cnt    = (int*)p; p += cnt_sz;
    int* rowptr = (int*)p; p += rp_sz;
    int* cursor = (int*)p; p += cur_sz;
    int* bsum   = (int*)p; p += bs_sz;
    int* perm   = (int*)p;

    // ---- W hi/lo split (tiny) ----
    convw_kernel<<<320, 256, 0, stream>>>(W_self, W_ring, wh, wl);

    // ---- CSR build ----
    hipMemsetAsync(cnt, 0, cnt_sz, stream);
    hist_kernel<<<dim3(NNZ / 256, RR), 256, 0, stream>>>(rows, cnt);
    scanA_kernel<<<dim3(NCHUNK, RR), 256, 0, stream>>>(cnt, bsum);
    scanB_kernel<<<1, 256, 0, stream>>>(bsum);
    scanC_kernel<<<dim3(NCHUNK, RR), 256, 0, stream>>>(cnt, bsum, rowptr, cursor);
    fill_kernel<<<dim3(NNZ / 256, RR), 256, 0, stream>>>(rows, cols, cursor, perm);

    if (big) {
        // one fused GEMM (all 640 cols), then one merged 4-ring gather
        gemm_kernel<<<NN / 16, 256, 0, stream>>>(x, wh, wl, odn, out, h, 0, 10, 0);
        gather_kernel<<<dim3(NN / 4, RR), 256, 0, stream>>>(h, rowptr, perm, out, 0);
    } else {
        // col-sliced: self block, then per-ring GEMM slice + gather (h reused)
        gemm_kernel<<<NN / 16, 256, 0, stream>>>(x, wh, wl, odn, out, h, 0, 2, 0);
        for (int r = 0; r < RR; ++r) {
            gemm_kernel<<<NN / 16, 256, 0, stream>>>(x, wh, wl, odn, out, h,
                                                     8 * (r + 1), 2, r);
            gather_kernel<<<dim3(NN / 4, 1), 256, 0, stream>>>(h, rowptr, perm, out, r);
        }
    }

    // ---- fused per-node interaction (in-place on d_out) ----
    const int gridI = 256;
    const int iters = (NN + gridI * 16 - 1) / (gridI * 16);
    interact_kernel<<<gridI, 1024, 0, stream>>>(out, WC, WD, att_w, att_b, idn, iters);
}

// Round 5
// 1157.623 us; speedup vs baseline: 3.5011x; 1.0547x over previous
//
#include <hip/hip_runtime.h>
#include <hip/hip_bf16.h>

#define NN 50000
#define D 128
#define RR 4
#define NNZ 800000
#define NCHUNK 196            // ceil(NN/256)

typedef float v2f    __attribute__((ext_vector_type(2)));
typedef float f32x4  __attribute__((ext_vector_type(4)));
typedef short bf16x8 __attribute__((ext_vector_type(8)));

static __device__ __forceinline__ unsigned short f2b(float f)
{
    __hip_bfloat16 h = __float2bfloat16(f);      // RNE
    return *reinterpret_cast<unsigned short*>(&h);
}
static __device__ __forceinline__ float b2f(unsigned short u)
{
    union { unsigned u32; float f; } v; v.u32 = ((unsigned)u) << 16; return v.f;
}

// ============================ CSR build =====================================
__global__ __launch_bounds__(256) void hist_kernel(
    const int* __restrict__ rows, int* __restrict__ cnt)
{
    const int r = blockIdx.y;
    const int e = blockIdx.x * 256 + threadIdx.x;      // NNZ = 3125*256 exact
    atomicAdd(&cnt[r * NN + rows[(size_t)r * NNZ + e]], 1);
}

__global__ __launch_bounds__(256) void scanA_kernel(
    const int* __restrict__ cnt, int* __restrict__ bsum)
{
    const int r = blockIdx.y, bx = blockIdx.x, t = threadIdx.x;
    const int idx = bx * 256 + t;
    int v = (idx < NN) ? cnt[r * NN + idx] : 0;
#pragma unroll
    for (int off = 32; off; off >>= 1) v += __shfl_xor(v, off);
    __shared__ int ws4[4];
    if ((t & 63) == 0) ws4[t >> 6] = v;
    __syncthreads();
    if (t == 0) bsum[r * NCHUNK + bx] = ws4[0] + ws4[1] + ws4[2] + ws4[3];
}

__global__ __launch_bounds__(256) void scanB_kernel(int* __restrict__ bsum)
{
    __shared__ int s[256];
    const int t = threadIdx.x;
    for (int r = 0; r < RR; ++r) {
        int v = (t < NCHUNK) ? bsum[r * NCHUNK + t] : 0;
        s[t] = v;
        __syncthreads();
        for (int off = 1; off < 256; off <<= 1) {
            int u = (t >= off) ? s[t - off] : 0;
            __syncthreads();
            s[t] += u;
            __syncthreads();
        }
        if (t < NCHUNK) bsum[r * NCHUNK + t] = s[t] - v;   // exclusive
        __syncthreads();
    }
}

__global__ __launch_bounds__(256) void scanC_kernel(
    const int* __restrict__ cnt, const int* __restrict__ bsum,
    int* __restrict__ rowptr, int* __restrict__ cursor)
{
    const int r = blockIdx.y, bx = blockIdx.x, t = threadIdx.x;
    const int idx = bx * 256 + t;
    int v = (idx < NN) ? cnt[r * NN + idx] : 0;
    __shared__ int s[256];
    s[t] = v;
    __syncthreads();
    for (int off = 1; off < 256; off <<= 1) {
        int u = (t >= off) ? s[t - off] : 0;
        __syncthreads();
        s[t] += u;
        __syncthreads();
    }
    const int excl = bsum[r * NCHUNK + bx] + s[t] - v;
    if (idx <= NN) rowptr[r * (NN + 1) + idx] = excl;
    if (idx < NN)  cursor[r * NN + idx] = excl;
}

__global__ __launch_bounds__(256) void fill_kernel(
    const int* __restrict__ rows, const int* __restrict__ cols,
    int* __restrict__ cursor, int* __restrict__ perm)
{
    const int r = blockIdx.y;
    const int e = blockIdx.x * 256 + threadIdx.x;
    const int row = rows[(size_t)r * NNZ + e];
    const int pos = atomicAdd(&cursor[r * NN + row], 1);
    perm[(size_t)r * NNZ + pos] = cols[(size_t)r * NNZ + e];
}

// ============================ W split to bf16 hi/lo =========================
// wh/wl[jg*128+k]: jg<128 -> W_self[jg][k], else W_rings flat row jg-128
__global__ __launch_bounds__(256) void convw_kernel(
    const float* __restrict__ Wself, const float* __restrict__ Wrings,
    unsigned short* __restrict__ wh, unsigned short* __restrict__ wl)
{
    int idx = blockIdx.x * 256 + threadIdx.x;    // 81920 elements
    int jg = idx >> 7, k = idx & 127;
    float f = (jg < 128) ? Wself[(size_t)jg * 128 + k]
                         : Wrings[(size_t)(jg - 128) * 128 + k];
    unsigned short hi = f2b(f);
    wh[idx] = hi;
    wl[idx] = f2b(f - b2f(hi));
}

// WC/WD transposed + split: wct_h[col*128+k] = bf16(WC[k][col]), etc.
// (fragment-ready layout for MFMA B operand of z3 @ WC)
__global__ __launch_bounds__(256) void convt_kernel(
    const float* __restrict__ WC, const float* __restrict__ WD,
    unsigned short* __restrict__ wct_h, unsigned short* __restrict__ wct_l,
    unsigned short* __restrict__ wdt_h, unsigned short* __restrict__ wdt_l)
{
    int idx = blockIdx.x * 256 + threadIdx.x;     // 16384, coalesced read
    int kk = idx >> 7, col = idx & 127;
    float c = WC[idx];                            // WC[kk*128+col]
    float d = WD[idx];
    unsigned short ch = f2b(c), dh = f2b(d);
    wct_h[col * 128 + kk] = ch;
    wct_l[col * 128 + kk] = f2b(c - b2f(ch));
    wdt_h[col * 128 + kk] = dh;
    wdt_l[col * 128 + kk] = f2b(d - b2f(dh));
}

// ============================ split-bf16 MFMA GEMM ==========================
// out_full[n][jg] = sum_k x[n][k] * W_all[jg][k],  jg in [0,640).
// product = xh*Wh + xl*Wh + xh*Wl (fp32-quality).
// ct<8 -> out slot0 f32; ct>=8 -> ring r=(ct>>3)-1-ring0, h fp32 * odn.
__global__ __launch_bounds__(256) void gemm_kernel(
    const float* __restrict__ x,
    const unsigned short* __restrict__ wh, const unsigned short* __restrict__ wl,
    const float* __restrict__ odn, float* __restrict__ out,
    float* __restrict__ h, int ct0, int nj, int ring0)
{
    const int t = threadIdx.x;
    const int w = t >> 6, l = t & 63;
    const int lr = l & 15, lk = l >> 4;
    const int n0 = blockIdx.x * 16;

    bf16x8 ah[4], al[4];
    const float* xr = x + (size_t)(n0 + lr) * D + lk * 8;
#pragma unroll
    for (int ks = 0; ks < 4; ++ks) {
        float4 v0 = *(const float4*)(xr + ks * 32);
        float4 v1 = *(const float4*)(xr + ks * 32 + 4);
        float f[8] = {v0.x, v0.y, v0.z, v0.w, v1.x, v1.y, v1.z, v1.w};
#pragma unroll
        for (int j = 0; j < 8; ++j) {
            unsigned short hi = f2b(f[j]);
            ah[ks][j] = (short)hi;
            al[ks][j] = (short)f2b(f[j] - b2f(hi));
        }
    }

    float od[4];
#pragma unroll
    for (int q = 0; q < 4; ++q) od[q] = odn[n0 + lk * 4 + q];

    for (int j = 0; j < nj; ++j) {
        const int ct = ct0 + w + 4 * j;
        const int colg = ct * 16 + lr;
        f32x4 acc = {0.f, 0.f, 0.f, 0.f};
#pragma unroll
        for (int ks = 0; ks < 4; ++ks) {
            bf16x8 bhv = *(const bf16x8*)&wh[(size_t)colg * D + ks * 32 + lk * 8];
            bf16x8 blv = *(const bf16x8*)&wl[(size_t)colg * D + ks * 32 + lk * 8];
            acc = __builtin_amdgcn_mfma_f32_16x16x32_bf16(ah[ks], bhv, acc, 0, 0, 0);
            acc = __builtin_amdgcn_mfma_f32_16x16x32_bf16(al[ks], bhv, acc, 0, 0, 0);
            acc = __builtin_amdgcn_mfma_f32_16x16x32_bf16(ah[ks], blv, acc, 0, 0, 0);
        }
        if (ct < 8) {
#pragma unroll
            for (int q = 0; q < 4; ++q) {
                int n = n0 + lk * 4 + q;
                out[(size_t)n * 640 + colg] = acc[q];
            }
        } else {
            const int r = (ct >> 3) - 1 - ring0;
            const int d = (ct & 7) * 16 + lr;
#pragma unroll
            for (int q = 0; q < 4; ++q) {
                int n = n0 + lk * 4 + q;
                h[((size_t)r * NN + n) * D + d] = acc[q] * od[q];
            }
        }
    }
}

// ============================ CSR gather (fp32 h) ===========================
__global__ __launch_bounds__(256) void gather_kernel(
    const float* __restrict__ h, const int* __restrict__ rp,
    const int* __restrict__ pm, float* __restrict__ z, int csr_base)
{
    const int hr = blockIdx.y;
    const int cr = hr + csr_base;
    const int ln = threadIdx.x & 63;
    const int row = blockIdx.x * 4 + (threadIdx.x >> 6);   // 12500*4 = 50000
    const int* rpr = rp + (size_t)cr * (NN + 1);
    const int s = rpr[row], e = rpr[row + 1];
    const float* hb = h + (size_t)hr * NN * D;
    const int* pmr = pm + (size_t)cr * NNZ;

    float2 acc = make_float2(0.f, 0.f);
    int i = s;
    for (; i + 4 <= e; i += 4) {
        int c0 = pmr[i], c1 = pmr[i + 1], c2 = pmr[i + 2], c3 = pmr[i + 3];
        float2 v0 = *(const float2*)&hb[(size_t)c0 * D + ln * 2];
        float2 v1 = *(const float2*)&hb[(size_t)c1 * D + ln * 2];
        float2 v2 = *(const float2*)&hb[(size_t)c2 * D + ln * 2];
        float2 v3 = *(const float2*)&hb[(size_t)c3 * D + ln * 2];
        acc.x += v0.x + v1.x + v2.x + v3.x;
        acc.y += v0.y + v1.y + v2.y + v3.y;
    }
    for (; i < e; ++i) {
        float2 v = *(const float2*)&hb[(size_t)pmr[i] * D + ln * 2];
        acc.x += v.x; acc.y += v.y;
    }
    *(float2*)&z[(size_t)row * 640 + (cr + 1) * 128 + ln * 2] = acc;
}

// ============================ interaction (MFMA) ============================
// Block = 512 thr (8 waves) = 16 nodes. M=80 rows (row = r*16+node), K=128,
// N=256 (WC | WD). Wave w: matrix mm=w>>2, N-quarter nq=w&3 (32 cols).
// A from global z (raw; idn folded in at phase C - linear transform).
// Results staged in SB[2][5][16][128] f32 (80 KB -> 2 blocks/CU), then
// scores/softmax/combine per node (wave w handles nodes w and w+8).
__device__ __forceinline__ int sidx(int r, int s)
{
    if (r > s) { int t = r; r = s; s = t; }
    return r * 5 + s - (r * (r + 1)) / 2;
}

__global__ __launch_bounds__(512, 4) void interact2_kernel(
    float* __restrict__ z,
    const unsigned short* __restrict__ wct_h, const unsigned short* __restrict__ wct_l,
    const unsigned short* __restrict__ wdt_h, const unsigned short* __restrict__ wdt_l,
    const float* __restrict__ att_w, const float* __restrict__ att_b,
    const float* __restrict__ idn)
{
    __shared__ float SB[2 * 5 * 16 * 128];    // 80 KB

    const int t  = threadIdx.x;
    const int w  = t >> 6;
    const int l  = t & 63;
    const int lr = l & 15;
    const int lk = l >> 4;
    const int n0 = blockIdx.x * 16;

    const int mm = w >> 2;
    const int nq = w & 3;
    const unsigned short* bhp = mm ? wdt_h : wct_h;
    const unsigned short* blp = mm ? wdt_l : wct_l;

    f32x4 acc[5][2];
#pragma unroll
    for (int mt = 0; mt < 5; ++mt) {
        acc[mt][0] = (f32x4){0.f, 0.f, 0.f, 0.f};
        acc[mt][1] = (f32x4){0.f, 0.f, 0.f, 0.f};
    }

#pragma unroll
    for (int mt = 0; mt < 5; ++mt) {
        // A-frags: 8 f32 from z row (node lr, ring mt), split hi/lo
        bf16x8 ah[4], al[4];
        const float* ap = z + (size_t)(n0 + lr) * 640 + mt * 128 + lk * 8;
#pragma unroll
        for (int ks = 0; ks < 4; ++ks) {
            float4 v0 = *(const float4*)(ap + ks * 32);
            float4 v1 = *(const float4*)(ap + ks * 32 + 4);
            float f[8] = {v0.x, v0.y, v0.z, v0.w, v1.x, v1.y, v1.z, v1.w};
#pragma unroll
            for (int j = 0; j < 8; ++j) {
                unsigned short hi = f2b(f[j]);
                ah[ks][j] = (short)hi;
                al[ks][j] = (short)f2b(f[j] - b2f(hi));
            }
        }
#pragma unroll
        for (int nt = 0; nt < 2; ++nt) {
            const int col = nq * 32 + nt * 16 + lr;
#pragma unroll
            for (int ks = 0; ks < 4; ++ks) {
                bf16x8 vh = *(const bf16x8*)&bhp[(size_t)col * 128 + ks * 32 + lk * 8];
                bf16x8 vl = *(const bf16x8*)&blp[(size_t)col * 128 + ks * 32 + lk * 8];
                acc[mt][nt] = __builtin_amdgcn_mfma_f32_16x16x32_bf16(ah[ks], vh, acc[mt][nt], 0, 0, 0);
                acc[mt][nt] = __builtin_amdgcn_mfma_f32_16x16x32_bf16(al[ks], vh, acc[mt][nt], 0, 0, 0);
                acc[mt][nt] = __builtin_amdgcn_mfma_f32_16x16x32_bf16(ah[ks], vl, acc[mt][nt], 0, 0, 0);
            }
        }
    }

    // ---- stage zc/zd to LDS: SB[mm][r=mt][node][col] ----
#pragma unroll
    for (int mt = 0; mt < 5; ++mt)
#pragma unroll
        for (int nt = 0; nt < 2; ++nt) {
            const int col = nq * 32 + nt * 16 + lr;
#pragma unroll
            for (int q = 0; q < 4; ++q) {
                const int nd = lk * 4 + q;                     // C row = node
                SB[(((mm * 5 + mt) * 16) + nd) * 128 + col] = acc[mt][nt][q];
            }
        }
    __syncthreads();

    // ---- phase C: per node (wave w -> nodes w, w+8), lane l -> cols 2l,2l+1
#pragma unroll
    for (int ii = 0; ii < 2; ++ii) {
        const int nd = w + ii * 8;
        const int n  = n0 + nd;
        const float nf = idn[n];

        v2f ar[5], dr[5];
#pragma unroll
        for (int r = 0; r < 5; ++r) {
            ar[r] = *(const v2f*)&SB[((r * 16) + nd) * 128 + 2 * l] * nf;
            dr[r] = *(const v2f*)&SB[(((5 + r) * 16) + nd) * 128 + 2 * l] * nf;
        }

        float pc[15], pd[15];
        {
            int k = 0;
#pragma unroll
            for (int r = 0; r < 5; ++r)
#pragma unroll
                for (int s = r; s < 5; ++s, ++k) {
                    v2f qc = ar[r] * ar[s];
                    v2f qd = dr[r] * dr[s];
                    float vc = qc.x + qc.y;
                    float vd = qd.x + qd.y;
#pragma unroll
                    for (int off = 32; off; off >>= 1) {
                        vc += __shfl_xor(vc, off);
                        vd += __shfl_xor(vd, off);
                    }
                    pc[k] = vc; pd[k] = vd;
                }
        }

        v2f zcom[5], zdis[5];
#pragma unroll
        for (int r = 0; r < 5; ++r) {
            float sc[5], m = -1e30f;
#pragma unroll
            for (int s = 0; s < 5; ++s) { sc[s] = pc[sidx(r, s)]; m = fmaxf(m, sc[s]); }
            float e[5], se = 0.f;
#pragma unroll
            for (int s = 0; s < 5; ++s) { e[s] = __expf(sc[s] - m); se += e[s]; }
            float inv = 1.f / se;
            v2f a2 = (v2f)0.f;
#pragma unroll
            for (int s = 0; s < 5; ++s) a2 += ar[s] * e[s];
            zcom[r] = a2 * inv;

            float qq = pd[sidx(r, r)];
            float sd[5], md = -1e30f;
#pragma unroll
            for (int s = 0; s < 5; ++s) { sd[s] = qq - pd[sidx(r, s)]; md = fmaxf(md, sd[s]); }
            float ed[5], sed = 0.f;
#pragma unroll
            for (int s = 0; s < 5; ++s) { ed[s] = __expf(sd[s] - md); sed += ed[s]; }
            float invd = 1.f / sed;
            v2f d2 = (v2f)0.f;
#pragma unroll
            for (int s = 0; s < 5; ++s) d2 += dr[s] * ed[s];
            zdis[r] = dr[r] - d2 * invd;       // sum_s a*(zd_r - zd_s)
        }

        v2f p2 = (v2f)0.f;
#pragma unroll
        for (int r = 0; r < 5; ++r) {
            p2 += (*(const v2f*)&att_w[r * 128 + 2 * l]) * zcom[r];
            p2 += (*(const v2f*)&att_w[640 + r * 128 + 2 * l]) * zdis[r];
        }
        float part = p2.x + p2.y;
#pragma unroll
        for (int off = 32; off; off >>= 1) part += __shfl_xor(part, off);
        const float beta = 1.f / (1.f + __expf(-(part + att_b[0])));
        const float omb  = 1.f - beta;

#pragma unroll
        for (int r = 0; r < 5; ++r) {
            v2f o = zcom[r] * beta + zdis[r] * omb;
            *(v2f*)&z[(size_t)n * 640 + r * 128 + 2 * l] = o;
        }
    }
}

// ============================ launch ========================================
extern "C" void kernel_launch(void* const* d_in, const int* in_sizes, int n_in,
                              void* d_out, int out_size, void* d_ws, size_t ws_size,
                              hipStream_t stream)
{
    const float* x      = (const float*)d_in[0];
    const float* W_self = (const float*)d_in[1];
    const float* W_ring = (const float*)d_in[2];
    const float* WC     = (const float*)d_in[3];
    const float* WD     = (const float*)d_in[4];
    const float* att_w  = (const float*)d_in[5];
    const float* att_b  = (const float*)d_in[6];
    const float* odn    = (const float*)d_in[7];
    const float* idn    = (const float*)d_in[8];
    const int*   rows   = (const int*)d_in[9];
    const int*   cols   = (const int*)d_in[10];
    float* out = (float*)d_out;

    // ---- workspace layout ----
    const size_t wb_sz  = (size_t)640 * 128 * 2;        // wh, wl
    const size_t wt_sz  = (size_t)128 * 128 * 2;        // wct_h/l, wdt_h/l
    const size_t h1_sz  = (size_t)NN * D * 4;           // 25.6 MB per ring
    const size_t cnt_sz = (size_t)RR * NN * 4;
    const size_t rp_sz  = (size_t)RR * (NN + 1) * 4;
    const size_t cur_sz = (size_t)RR * NN * 4;
    const size_t bs_sz  = 4096;
    const size_t pm_sz  = (size_t)RR * NNZ * 4;
    const size_t fixed  = 2 * wb_sz + 4 * wt_sz + cnt_sz + rp_sz + cur_sz + bs_sz + pm_sz;
    const bool big = ws_size >= fixed + RR * h1_sz + 4096;   // ~118.3 MB

    char* p = (char*)d_ws;
    unsigned short* wh    = (unsigned short*)p; p += wb_sz;
    unsigned short* wl    = (unsigned short*)p; p += wb_sz;
    unsigned short* wct_h = (unsigned short*)p; p += wt_sz;
    unsigned short* wct_l = (unsigned short*)p; p += wt_sz;
    unsigned short* wdt_h = (unsigned short*)p; p += wt_sz;
    unsigned short* wdt_l = (unsigned short*)p; p += wt_sz;
    float* h    = (float*)p; p += (big ? RR : 1) * h1_sz;
    int* cnt    = (int*)p; p += cnt_sz;
    int* rowptr = (int*)p; p += rp_sz;
    int* cursor = (int*)p; p += cur_sz;
    int* bsum   = (int*)p; p += bs_sz;
    int* perm   = (int*)p;

    // ---- weight conversions (tiny) ----
    convw_kernel<<<320, 256, 0, stream>>>(W_self, W_ring, wh, wl);
    convt_kernel<<<64, 256, 0, stream>>>(WC, WD, wct_h, wct_l, wdt_h, wdt_l);

    // ---- CSR build ----
    hipMemsetAsync(cnt, 0, cnt_sz, stream);
    hist_kernel<<<dim3(NNZ / 256, RR), 256, 0, stream>>>(rows, cnt);
    scanA_kernel<<<dim3(NCHUNK, RR), 256, 0, stream>>>(cnt, bsum);
    scanB_kernel<<<1, 256, 0, stream>>>(bsum);
    scanC_kernel<<<dim3(NCHUNK, RR), 256, 0, stream>>>(cnt, bsum, rowptr, cursor);
    fill_kernel<<<dim3(NNZ / 256, RR), 256, 0, stream>>>(rows, cols, cursor, perm);

    if (big) {
        gemm_kernel<<<NN / 16, 256, 0, stream>>>(x, wh, wl, odn, out, h, 0, 10, 0);
        gather_kernel<<<dim3(NN / 4, RR), 256, 0, stream>>>(h, rowptr, perm, out, 0);
    } else {
        gemm_kernel<<<NN / 16, 256, 0, stream>>>(x, wh, wl, odn, out, h, 0, 2, 0);
        for (int r = 0; r < RR; ++r) {
            gemm_kernel<<<NN / 16, 256, 0, stream>>>(x, wh, wl, odn, out, h,
                                                     8 * (r + 1), 2, r);
            gather_kernel<<<dim3(NN / 4, 1), 256, 0, stream>>>(h, rowptr, perm, out, r);
        }
    }

    // ---- fused per-node interaction (in-place on d_out) ----
    interact2_kernel<<<NN / 16, 512, 0, stream>>>(out, wct_h, wct_l, wdt_h, wdt_l,
                                                  att_w, att_b, idn);
}